// Round 1
// 2325.554 us; speedup vs baseline: 1.2906x; 1.2906x over previous
//
#include <hip/hip_runtime.h>
#include <stdint.h>

#define IN_F 512
#define HID  256
#define CLS  64
#define KPOW 10

typedef unsigned short ushort_t;

__device__ __forceinline__ float b2f(ushort_t u) {
    union { unsigned u; float f; } x; x.u = ((unsigned)u) << 16; return x.f;
}
__device__ __forceinline__ ushort_t f2b(float f) {
    union { float f; unsigned u; } x; x.f = f;
    unsigned u = x.u;
    u += 0x7fffu + ((u >> 16) & 1u);   // round-to-nearest-even
    return (ushort_t)(u >> 16);
}

// ---- dtype probes: flags[0]=float-inputs-are-fp32, flags[1]=edges-are-int64
__global__ void k_probe(const ushort_t* __restrict__ feat,
                        const int* __restrict__ eidx,
                        int* __restrict__ flags) {
    if (threadIdx.x == 0 && blockIdx.x == 0) {
        int sane = 0;
        for (int i = 0; i < 128; ++i) {
            unsigned u = (unsigned)feat[2 * i] & 0x7fffu;
            unsigned e = u >> 7;
            if (u == 0u || (e >= 100u && e <= 140u)) sane++;
        }
        flags[0] = (sane == 128) ? 0 : 1;   // 1 => fp32 inputs
        int nz = 0;
        for (int i = 0; i < 128; ++i) nz |= eidx[2 * i + 1];
        flags[1] = (nz == 0) ? 1 : 0;       // 1 => int64 edges
    }
}

__device__ __forceinline__ int edge_at(const int* __restrict__ e, long long i, int wide) {
    return wide ? (int)(((const long long*)e)[i]) : e[i];
}

// ---------------- degree histogram ----------------
__global__ void k_degree(const int* __restrict__ eidx, int E,
                         unsigned* __restrict__ oc, unsigned* __restrict__ ic,
                         const int* __restrict__ flags) {
    const int wide = flags[1];
    int e = blockIdx.x * blockDim.x + threadIdx.x;
    if (e < E) {
        atomicAdd(&oc[edge_at(eidx, e, wide)], 1u);
        atomicAdd(&ic[edge_at(eidx, (long long)E + e, wide)], 1u);
    }
}

// ---------------- norms: ns = rsqrt(max(outdeg,1)), nd9 = 0.9*rsqrt(max(indeg,1))
__global__ void k_norm(const unsigned* __restrict__ oc, const unsigned* __restrict__ ic,
                       float* __restrict__ ns, float* __restrict__ nd9, int N) {
    int i = blockIdx.x * blockDim.x + threadIdx.x;
    if (i < N) {
        ns[i]  = rsqrtf(fmaxf((float)oc[i], 1.0f));
        nd9[i] = 0.9f * rsqrtf(fmaxf((float)ic[i], 1.0f));
    }
}

// ---------------- single-block exclusive scan (wave-shuffle based) ----------
__global__ void k_scan(const unsigned* __restrict__ cnt, int n,
                       int* __restrict__ offs, int* __restrict__ cursor) {
    __shared__ unsigned ws[16];
    __shared__ unsigned tot;
    const int t    = threadIdx.x;        // 0..1023
    const int lane = t & 63;
    const int wid  = t >> 6;
    unsigned carry = 0;
    for (int base = 0; base < n; base += 1024) {
        const int i = base + t;
        const unsigned v = (i < n) ? cnt[i] : 0u;
        // inclusive scan within wave (64 lanes)
        unsigned x = v;
        #pragma unroll
        for (int d = 1; d < 64; d <<= 1) {
            unsigned y = __shfl_up(x, d);
            if (lane >= d) x += y;
        }
        if (lane == 63) ws[wid] = x;
        __syncthreads();
        // wave 0 scans the 16 per-wave totals
        if (wid == 0) {
            const unsigned wv = (lane < 16) ? ws[lane] : 0u;
            unsigned wx = wv;
            #pragma unroll
            for (int d = 1; d < 16; d <<= 1) {
                unsigned y = __shfl_up(wx, d);
                if (lane >= d) wx += y;
            }
            if (lane < 16) ws[lane] = wx - wv;   // exclusive prefix of wave sums
            if (lane == 15) tot = wx;            // inclusive total of this tile
        }
        __syncthreads();
        if (i < n) {
            const int o = (int)(carry + ws[wid] + (x - v));
            offs[i]   = o;
            cursor[i] = o;
        }
        carry += tot;
        __syncthreads();   // protect ws/tot from next-iteration overwrite
    }
    if (t == 0) offs[n] = (int)carry;
}

// ---------------- scatter edges into CSR-by-dst (payload = src only) --------
__global__ void k_scatter(const int* __restrict__ eidx, int E,
                          int* __restrict__ cursor, int* __restrict__ esrc,
                          const int* __restrict__ flags) {
    const int wide = flags[1];
    int e = blockIdx.x * blockDim.x + threadIdx.x;
    if (e < E) {
        int s = edge_at(eidx, e, wide);
        int d = edge_at(eidx, (long long)E + e, wide);
        int pos = atomicAdd(&cursor[d], 1);
        esrc[pos] = s;
    }
}

// ---------------- tiled GEMM: C = act(A[MxK] * B[KxN] + bias) ---------------
template<int BK, bool RELU, bool OUT_BF16, bool A_DYN>
__global__ __launch_bounds__(256) void k_gemm(const void* __restrict__ Av,
                                              const void* __restrict__ Bv,
                                              const void* __restrict__ biasv,
                                              void* __restrict__ Cv,
                                              int M, int N, int K,
                                              const int* __restrict__ flags) {
    constexpr int BM = 64, BN = 64;
    __shared__ float As[BK][BM + 4];
    __shared__ float Bs[BK][BN + 4];

    const int f32 = flags[0];
    const bool aF32 = A_DYN && (f32 != 0);
    const bool bF32 = (f32 != 0);

    const int tid = threadIdx.x;
    const int tx  = tid & 15;
    const int ty  = tid >> 4;
    const int rowBase = blockIdx.x * BM;
    const int colBase = blockIdx.y * BN;

    float acc[4][4] = {};

    for (int kt = 0; kt < K; kt += BK) {
        #pragma unroll
        for (int l = 0; l < (BM * BK) / (256 * 4); ++l) {
            int eidx = (l * 256 + tid) * 4;
            int m = eidx / BK;
            int k = eidx % BK;
            int gr = rowBase + m; if (gr >= M) gr = M - 1;
            size_t off = (size_t)gr * K + kt + k;
            float4 f;
            if (aF32) {
                f = *(const float4*)((const float*)Av + off);
            } else {
                const ushort4 v = *(const ushort4*)((const ushort_t*)Av + off);
                f = make_float4(b2f(v.x), b2f(v.y), b2f(v.z), b2f(v.w));
            }
            As[k + 0][m] = f.x;
            As[k + 1][m] = f.y;
            As[k + 2][m] = f.z;
            As[k + 3][m] = f.w;
        }
        #pragma unroll
        for (int l = 0; l < (BK * BN) / (256 * 4); ++l) {
            int eidx = (l * 256 + tid) * 4;
            int k = eidx / BN;
            int n = eidx % BN;
            size_t off = (size_t)(kt + k) * N + colBase + n;
            float4 f;
            if (bF32) {
                f = *(const float4*)((const float*)Bv + off);
            } else {
                const ushort4 v = *(const ushort4*)((const ushort_t*)Bv + off);
                f = make_float4(b2f(v.x), b2f(v.y), b2f(v.z), b2f(v.w));
            }
            *(float4*)&Bs[k][n] = f;
        }
        __syncthreads();

        #pragma unroll
        for (int kk = 0; kk < BK; ++kk) {
            const float4 a = *(const float4*)&As[kk][ty * 4];
            const float4 b = *(const float4*)&Bs[kk][tx * 4];
            const float av[4] = {a.x, a.y, a.z, a.w};
            const float bv[4] = {b.x, b.y, b.z, b.w};
            #pragma unroll
            for (int i = 0; i < 4; ++i)
                #pragma unroll
                for (int j = 0; j < 4; ++j)
                    acc[i][j] = fmaf(av[i], bv[j], acc[i][j]);
        }
        __syncthreads();
    }

    float bv[4];
    #pragma unroll
    for (int j = 0; j < 4; ++j) {
        int c = colBase + tx * 4 + j;
        bv[j] = bF32 ? ((const float*)biasv)[c] : b2f(((const ushort_t*)biasv)[c]);
    }

    #pragma unroll
    for (int i = 0; i < 4; ++i) {
        int row = rowBase + ty * 4 + i;
        if (row < M) {
            #pragma unroll
            for (int j = 0; j < 4; ++j) {
                float v = acc[i][j] + bv[j];
                if (RELU) v = fmaxf(v, 0.0f);
                size_t idx = (size_t)row * N + colBase + tx * 4 + j;
                if (OUT_BF16) ((ushort_t*)Cv)[idx] = f2b(v);
                else          ((float*)Cv)[idx]    = v;
            }
        }
    }
}

// ---- after GEMM2: g0 = ns*h0 ; a0 = 0.1*h0 (in place over h0) --------------
__global__ void k_init(float* __restrict__ h0a0, float* __restrict__ g0,
                       const float* __restrict__ ns, int total) {
    int i = blockIdx.x * blockDim.x + threadIdx.x;
    if (i < total) {
        float v = h0a0[i];
        g0[i]   = ns[i >> 6] * v;
        h0a0[i] = 0.1f * v;
    }
}

// ---- pull propagation on g: h = nd9[v]*sum(g[src]) + a0[v]; g' = ns[v]*h ---
// Lane remap: sub = lane>>4 picks one of 4 edges, q = lane&15 picks a float4
// class quad. One global_load_dwordx4 gathers 4 rows x 16B = 1 KB per wave.
// LAST=true writes h itself (fp32, d_out is float per reference output dtype).
template<bool LAST>
__global__ __launch_bounds__(256) void k_prop(const float* __restrict__ g,
                                              const float* __restrict__ a0,
                                              const int* __restrict__ esrc,
                                              const int* __restrict__ offs,
                                              const float* __restrict__ nd9,
                                              const float* __restrict__ ns,
                                              float* __restrict__ out, int N) {
    const int lane = threadIdx.x & 63;
    const int wid  = threadIdx.x >> 6;
    const int v    = blockIdx.x * 4 + wid;
    if (v >= N) return;

    const int sub = lane >> 4;          // edge slot within group of 4
    const int q4  = (lane & 15) << 2;   // class quad base (0,4,...,60)
    const int start = offs[v];
    const int end   = offs[v + 1];

    float a0x = 0.f, a0y = 0.f, a0z = 0.f, a0w = 0.f;
    float a1x = 0.f, a1y = 0.f, a1z = 0.f, a1w = 0.f;
    float a2x = 0.f, a2y = 0.f, a2z = 0.f, a2w = 0.f;
    float a3x = 0.f, a3y = 0.f, a3z = 0.f, a3w = 0.f;

    int i = start;
    // 16 edges per iteration: 4 independent 1KB gathers in flight
    for (; i + 16 <= end; i += 16) {
        const int s0 = esrc[i      + sub];
        const int s1 = esrc[i + 4  + sub];
        const int s2 = esrc[i + 8  + sub];
        const int s3 = esrc[i + 12 + sub];
        const float4 g0 = *(const float4*)&g[(size_t)s0 * CLS + q4];
        const float4 g1 = *(const float4*)&g[(size_t)s1 * CLS + q4];
        const float4 g2 = *(const float4*)&g[(size_t)s2 * CLS + q4];
        const float4 g3 = *(const float4*)&g[(size_t)s3 * CLS + q4];
        a0x += g0.x; a0y += g0.y; a0z += g0.z; a0w += g0.w;
        a1x += g1.x; a1y += g1.y; a1z += g1.z; a1w += g1.w;
        a2x += g2.x; a2y += g2.y; a2z += g2.z; a2w += g2.w;
        a3x += g3.x; a3y += g3.y; a3z += g3.z; a3w += g3.w;
    }
    // 4-edge steps
    for (; i + 4 <= end; i += 4) {
        const int s0 = esrc[i + sub];
        const float4 g0 = *(const float4*)&g[(size_t)s0 * CLS + q4];
        a0x += g0.x; a0y += g0.y; a0z += g0.z; a0w += g0.w;
    }
    // tail (1..3 edges): only lane groups with sub < rem participate
    if (i < end) {
        const int rem = end - i;
        if (sub < rem) {
            const int s0 = esrc[i + sub];
            const float4 g0 = *(const float4*)&g[(size_t)s0 * CLS + q4];
            a0x += g0.x; a0y += g0.y; a0z += g0.z; a0w += g0.w;
        }
    }

    float rx = a0x + a1x + a2x + a3x;
    float ry = a0y + a1y + a2y + a3y;
    float rz = a0z + a1z + a2z + a3z;
    float rw = a0w + a1w + a2w + a3w;
    // combine the 4 edge-slot groups (lanes l, l^16, l^32, l^48)
    rx += __shfl_xor(rx, 16); rx += __shfl_xor(rx, 32);
    ry += __shfl_xor(ry, 16); ry += __shfl_xor(ry, 32);
    rz += __shfl_xor(rz, 16); rz += __shfl_xor(rz, 32);
    rw += __shfl_xor(rw, 16); rw += __shfl_xor(rw, 32);

    if (sub == 0) {
        const size_t idx = (size_t)v * CLS + q4;
        const float4 t0 = *(const float4*)&a0[idx];
        const float c = nd9[v];
        float hx = fmaf(c, rx, t0.x);
        float hy = fmaf(c, ry, t0.y);
        float hz = fmaf(c, rz, t0.z);
        float hw = fmaf(c, rw, t0.w);
        if (!LAST) {
            const float s = ns[v];
            hx *= s; hy *= s; hz *= s; hw *= s;
        }
        float4 o = make_float4(hx, hy, hz, hw);
        *(float4*)&out[idx] = o;
    }
}

extern "C" void kernel_launch(void* const* d_in, const int* in_sizes, int n_in,
                              void* d_out, int out_size, void* d_ws, size_t ws_size,
                              hipStream_t stream) {
    const ushort_t* feat = (const ushort_t*)d_in[0];
    const int*      eidx = (const int*)d_in[1];
    const void*     W1   = d_in[2];
    const void*     b1   = d_in[3];
    const void*     W2   = d_in[4];
    const void*     b2   = d_in[5];

    const int N = in_sizes[0] / IN_F;
    const int E = in_sizes[1] / 2;

    char* w = (char*)d_ws;
    auto take = [&](size_t bytes) -> char* {
        char* p = w; w += (bytes + 255) & ~(size_t)255; return p;
    };
    int*      flags = (int*)take(256);
    unsigned* oc    = (unsigned*)take((size_t)N * 4);
    unsigned* ic    = (unsigned*)take((size_t)N * 4);
    float*    ns    = (float*)take((size_t)N * 4);
    float*    nd9   = (float*)take((size_t)N * 4);
    int*      offs  = (int*)take((size_t)(N + 1) * 4);
    int*      curs  = (int*)take((size_t)N * 4);
    int*      esrc  = (int*)take((size_t)E * 4);
    float*    h0a0  = (float*)take((size_t)N * CLS * 4);          // h0 then a0
    char*     regG  = take((size_t)N * HID * 2);                  // H1 (bf16), then gA|gB
    ushort_t* H1 = (ushort_t*)regG;
    float*    gA = (float*)regG;
    float*    gB = (float*)(regG + (size_t)N * CLS * 4);

    hipMemsetAsync(oc, 0, (size_t)N * 4, stream);
    hipMemsetAsync(ic, 0, (size_t)N * 4, stream);

    k_probe<<<1, 64, 0, stream>>>(feat, eidx, flags);

    const int gE = (E + 255) / 256;
    k_degree<<<gE, 256, 0, stream>>>(eidx, E, oc, ic, flags);
    k_norm<<<(N + 255) / 256, 256, 0, stream>>>(oc, ic, ns, nd9, N);
    k_scan<<<1, 1024, 0, stream>>>(ic, N, offs, curs);
    k_scatter<<<gE, 256, 0, stream>>>(eidx, E, curs, esrc, flags);

    dim3 g1((N + 63) / 64, HID / 64);
    k_gemm<32, true,  true,  true ><<<g1, 256, 0, stream>>>(feat, W1, b1, (void*)H1, N, HID, IN_F, flags);
    dim3 g2((N + 63) / 64, CLS / 64);
    k_gemm<32, false, false, false><<<g2, 256, 0, stream>>>(H1, W2, b2, (void*)h0a0, N, CLS, HID, flags);

    const int total = N * CLS;
    k_init<<<(total + 255) / 256, 256, 0, stream>>>(h0a0, gA, ns, total);

    const int gp = (N + 3) / 4;
    for (int it = 0; it < KPOW; ++it) {
        const float* gin = (it & 1) ? gB : gA;
        if (it == KPOW - 1) {
            k_prop<true ><<<gp, 256, 0, stream>>>(gin, h0a0, esrc, offs, nd9, ns, (float*)d_out, N);
        } else {
            float* gout = (it & 1) ? gA : gB;
            k_prop<false><<<gp, 256, 0, stream>>>(gin, h0a0, esrc, offs, nd9, ns, gout, N);
        }
    }
}

// Round 2
// 1570.629 us; speedup vs baseline: 1.9109x; 1.4807x over previous
//
#include <hip/hip_runtime.h>
#include <stdint.h>

#define IN_F 512
#define HID  256
#define CLS  64
#define KPOW 10

typedef unsigned short ushort_t;

typedef __attribute__((ext_vector_type(8))) __bf16    bf16x8;
typedef __attribute__((ext_vector_type(4))) float     f32x4;
typedef __attribute__((ext_vector_type(8))) short     s16x8;
typedef __attribute__((ext_vector_type(8))) _Float16  f16x8;
typedef __attribute__((ext_vector_type(4))) _Float16  f16x4;

__device__ __forceinline__ float b2f(ushort_t u) {
    union { unsigned u; float f; } x; x.u = ((unsigned)u) << 16; return x.f;
}
__device__ __forceinline__ ushort_t f2b(float f) {
    union { float f; unsigned u; } x; x.f = f;
    unsigned u = x.u;
    u += 0x7fffu + ((u >> 16) & 1u);   // round-to-nearest-even
    return (ushort_t)(u >> 16);
}

// async global->LDS, 16B per lane; lds dest must be wave-uniform base (+lane*16)
__device__ __forceinline__ void gll16(const void* g, void* l) {
    __builtin_amdgcn_global_load_lds(
        (const __attribute__((address_space(1))) unsigned int*)g,
        (__attribute__((address_space(3))) unsigned int*)l, 16, 0, 0);
}

// ---- dtype probes: flags[0]=float-inputs-are-fp32, flags[1]=edges-are-int64
__global__ void k_probe(const ushort_t* __restrict__ feat,
                        const int* __restrict__ eidx,
                        int* __restrict__ flags) {
    if (threadIdx.x == 0 && blockIdx.x == 0) {
        int sane = 0;
        for (int i = 0; i < 128; ++i) {
            unsigned u = (unsigned)feat[2 * i] & 0x7fffu;
            unsigned e = u >> 7;
            if (u == 0u || (e >= 100u && e <= 140u)) sane++;
        }
        flags[0] = (sane == 128) ? 0 : 1;   // 1 => fp32 inputs
        int nz = 0;
        for (int i = 0; i < 128; ++i) nz |= eidx[2 * i + 1];
        flags[1] = (nz == 0) ? 1 : 0;       // 1 => int64 edges
    }
}

__device__ __forceinline__ int edge_at(const int* __restrict__ e, long long i, int wide) {
    return wide ? (int)(((const long long*)e)[i]) : e[i];
}

// ---------------- degree histogram ----------------
__global__ void k_degree(const int* __restrict__ eidx, int E,
                         unsigned* __restrict__ oc, unsigned* __restrict__ ic,
                         const int* __restrict__ flags) {
    const int wide = flags[1];
    int e = blockIdx.x * blockDim.x + threadIdx.x;
    if (e < E) {
        atomicAdd(&oc[edge_at(eidx, e, wide)], 1u);
        atomicAdd(&ic[edge_at(eidx, (long long)E + e, wide)], 1u);
    }
}

// ---------------- norms ----------------
__global__ void k_norm(const unsigned* __restrict__ oc, const unsigned* __restrict__ ic,
                       float* __restrict__ ns, float* __restrict__ nd9, int N) {
    int i = blockIdx.x * blockDim.x + threadIdx.x;
    if (i < N) {
        ns[i]  = rsqrtf(fmaxf((float)oc[i], 1.0f));
        nd9[i] = 0.9f * rsqrtf(fmaxf((float)ic[i], 1.0f));
    }
}

// ---------------- single-block exclusive scan (wave-shuffle based) ----------
__global__ void k_scan(const unsigned* __restrict__ cnt, int n,
                       int* __restrict__ offs, int* __restrict__ cursor) {
    __shared__ unsigned ws[16];
    __shared__ unsigned tot;
    const int t    = threadIdx.x;        // 0..1023
    const int lane = t & 63;
    const int wid  = t >> 6;
    unsigned carry = 0;
    for (int base = 0; base < n; base += 1024) {
        const int i = base + t;
        const unsigned v = (i < n) ? cnt[i] : 0u;
        unsigned x = v;
        #pragma unroll
        for (int d = 1; d < 64; d <<= 1) {
            unsigned y = __shfl_up(x, d);
            if (lane >= d) x += y;
        }
        if (lane == 63) ws[wid] = x;
        __syncthreads();
        if (wid == 0) {
            const unsigned wv = (lane < 16) ? ws[lane] : 0u;
            unsigned wx = wv;
            #pragma unroll
            for (int d = 1; d < 16; d <<= 1) {
                unsigned y = __shfl_up(wx, d);
                if (lane >= d) wx += y;
            }
            if (lane < 16) ws[lane] = wx - wv;
            if (lane == 15) tot = wx;
        }
        __syncthreads();
        if (i < n) {
            const int o = (int)(carry + ws[wid] + (x - v));
            offs[i]   = o;
            cursor[i] = o;
        }
        carry += tot;
        __syncthreads();
    }
    if (t == 0) offs[n] = (int)carry;
}

// ---------------- scatter edges into CSR-by-dst ----------------
__global__ void k_scatter(const int* __restrict__ eidx, int E,
                          int* __restrict__ cursor, int* __restrict__ esrc,
                          const int* __restrict__ flags) {
    const int wide = flags[1];
    int e = blockIdx.x * blockDim.x + threadIdx.x;
    if (e < E) {
        int s = edge_at(eidx, e, wide);
        int d = edge_at(eidx, (long long)E + e, wide);
        int pos = atomicAdd(&cursor[d], 1);
        esrc[pos] = s;
    }
}

// ---- pre-transpose weights to bf16 [N][K] and biases to fp32 ---------------
__global__ void k_prepw(const void* __restrict__ W1, const void* __restrict__ W2,
                        const void* __restrict__ b1, const void* __restrict__ b2,
                        ushort_t* __restrict__ W1t, ushort_t* __restrict__ W2t,
                        float* __restrict__ bias1, float* __restrict__ bias2,
                        const int* __restrict__ flags) {
    const int f32 = flags[0];
    const int stride = gridDim.x * blockDim.x;
    int t = blockIdx.x * blockDim.x + threadIdx.x;
    for (int i = t; i < IN_F * HID; i += stride) {
        int k = i / HID, n = i % HID;       // coalesced read over n
        float v = f32 ? ((const float*)W1)[i] : b2f(((const ushort_t*)W1)[i]);
        W1t[(size_t)n * IN_F + k] = f2b(v);
    }
    for (int i = t; i < HID * CLS; i += stride) {
        int k = i / CLS, n = i % CLS;
        float v = f32 ? ((const float*)W2)[i] : b2f(((const ushort_t*)W2)[i]);
        W2t[(size_t)n * HID + k] = f2b(v);
    }
    if (t < HID) bias1[t] = f32 ? ((const float*)b1)[t] : b2f(((const ushort_t*)b1)[t]);
    if (t < CLS) bias2[t] = f32 ? ((const float*)b2)[t] : b2f(((const ushort_t*)b2)[t]);
}

// ---------------- MFMA GEMM: C[M][BN] = act(X[M][K] * W[K][BN] + bias) ------
// A-operand = Wt rows (n), B-operand = X rows (m); D: col(lane&15)=m,
// row((lane>>4)*4+reg)=n  [C/D layout HW-verified]. LDS rows are 128B with the
// XOR-16B-chunk swizzle (chunk ^= row&7) to kill the 32-way bank conflict;
// Ws is filled by global_load_lds with the inverse swizzle applied to the
// global source address (linear LDS dest), Xs is reg-staged (handles fp32
// or bf16 input) with the swizzle applied on the ds_write address.
template<int BM, int BN, int WM, int WN, int MF, int NF, bool RELU, bool OUT_BF16, bool A_DYN>
__global__ __launch_bounds__(256) void k_gemm_mfma(const void* __restrict__ Xv,
                                                   const ushort_t* __restrict__ Wt,
                                                   const float* __restrict__ biasf,
                                                   void* __restrict__ Cv,
                                                   int M, int K,
                                                   const int* __restrict__ flags) {
    __shared__ ushort_t Ws[BN * 64];
    __shared__ ushort_t Xs[BM * 64];

    const bool xF32 = A_DYN ? (flags[0] != 0) : false;
    const int tid  = threadIdx.x;
    const int lane = tid & 63;
    const int wid  = tid >> 6;
    const int wr   = wid / WN;
    const int wc   = wid % WN;
    const int l15  = lane & 15;
    const int lhi  = lane >> 4;
    const int mbase = blockIdx.x * BM;

    f32x4 acc[MF][NF];
    #pragma unroll
    for (int mf = 0; mf < MF; ++mf)
        #pragma unroll
        for (int nf = 0; nf < NF; ++nf)
            acc[mf][nf] = (f32x4){0.f, 0.f, 0.f, 0.f};

    for (int kt = 0; kt < K; kt += 64) {
        // ---- stage W tile (bf16, pre-transposed) via global_load_lds
        constexpr int CW = (BN * 8) / 256;
        #pragma unroll
        for (int i = 0; i < CW; ++i) {
            const int cid = i * 256 + tid;
            const int n   = cid >> 3;
            const int c   = (cid & 7) ^ (n & 7);           // inverse swizzle on src
            const ushort_t* src = Wt + (size_t)n * K + kt + c * 8;
            void* dst = (void*)((char*)Ws + (size_t)(i * 256 + wid * 64) * 16);
            gll16((const void*)src, dst);
        }
        // ---- stage X tile (convert to bf16 if needed), swizzled ds_write
        constexpr int CX = (BM * 8) / 256;
        #pragma unroll
        for (int i = 0; i < CX; ++i) {
            const int cid = i * 256 + tid;
            const int m   = cid >> 3;
            const int c0  = cid & 7;
            int gr = mbase + m; if (gr >= M) gr = M - 1;
            s16x8 val;
            if (xF32) {
                const float* xp = (const float*)Xv + (size_t)gr * K + kt + c0 * 8;
                const float4 f0 = *(const float4*)(xp);
                const float4 f1 = *(const float4*)(xp + 4);
                val[0] = (short)f2b(f0.x); val[1] = (short)f2b(f0.y);
                val[2] = (short)f2b(f0.z); val[3] = (short)f2b(f0.w);
                val[4] = (short)f2b(f1.x); val[5] = (short)f2b(f1.y);
                val[6] = (short)f2b(f1.z); val[7] = (short)f2b(f1.w);
            } else {
                val = *(const s16x8*)((const ushort_t*)Xv + (size_t)gr * K + kt + c0 * 8);
            }
            *(s16x8*)&Xs[(size_t)(m * 8 + (c0 ^ (m & 7))) * 8] = val;
        }
        __syncthreads();

        #pragma unroll
        for (int ks = 0; ks < 2; ++ks) {
            const int k4 = ks * 4 + lhi;
            bf16x8 wf[NF];
            bf16x8 xf[MF];
            #pragma unroll
            for (int nf = 0; nf < NF; ++nf) {
                const int n = wc * (NF * 16) + nf * 16 + l15;
                wf[nf] = *(const bf16x8*)&Ws[(size_t)(n * 8 + (k4 ^ (n & 7))) * 8];
            }
            #pragma unroll
            for (int mf = 0; mf < MF; ++mf) {
                const int m = wr * (MF * 16) + mf * 16 + l15;
                xf[mf] = *(const bf16x8*)&Xs[(size_t)(m * 8 + (k4 ^ (m & 7))) * 8];
            }
            #pragma unroll
            for (int mf = 0; mf < MF; ++mf)
                #pragma unroll
                for (int nf = 0; nf < NF; ++nf)
                    acc[mf][nf] = __builtin_amdgcn_mfma_f32_16x16x32_bf16(
                        wf[nf], xf[mf], acc[mf][nf], 0, 0, 0);
        }
        __syncthreads();
    }

    // ---- epilogue: lane holds 4 contiguous n (regs) for one m per frag
    #pragma unroll
    for (int nf = 0; nf < NF; ++nf) {
        const int nb = wc * (NF * 16) + nf * 16 + lhi * 4;
        const float4 bb = *(const float4*)&biasf[nb];
        #pragma unroll
        for (int mf = 0; mf < MF; ++mf) {
            const int row = mbase + wr * (MF * 16) + mf * 16 + l15;
            if (row < M) {
                float v0 = acc[mf][nf][0] + bb.x;
                float v1 = acc[mf][nf][1] + bb.y;
                float v2 = acc[mf][nf][2] + bb.z;
                float v3 = acc[mf][nf][3] + bb.w;
                if (RELU) {
                    v0 = fmaxf(v0, 0.f); v1 = fmaxf(v1, 0.f);
                    v2 = fmaxf(v2, 0.f); v3 = fmaxf(v3, 0.f);
                }
                if (OUT_BF16) {
                    ushort4 o;
                    o.x = f2b(v0); o.y = f2b(v1); o.z = f2b(v2); o.w = f2b(v3);
                    *(ushort4*)((ushort_t*)Cv + (size_t)row * BN + nb) = o;
                } else {
                    *(float4*)((float*)Cv + (size_t)row * BN + nb) = make_float4(v0, v1, v2, v3);
                }
            }
        }
    }
}

// ---- after GEMM2: g0 = fp16(ns*h0) ; a0 = 0.1*h0 (in place) ----------------
__global__ void k_init(float* __restrict__ h0a0, _Float16* __restrict__ g0,
                       const float* __restrict__ ns, int total4) {
    int i = blockIdx.x * blockDim.x + threadIdx.x;
    if (i < total4) {
        const int base = i * 4;
        float4 v = *(const float4*)&h0a0[base];
        const float s = ns[base >> 6];
        f16x4 o;
        o[0] = (_Float16)(s * v.x); o[1] = (_Float16)(s * v.y);
        o[2] = (_Float16)(s * v.z); o[3] = (_Float16)(s * v.w);
        *(f16x4*)&g0[base] = o;
        *(float4*)&h0a0[base] = make_float4(0.1f * v.x, 0.1f * v.y, 0.1f * v.z, 0.1f * v.w);
    }
}

// ---- pull propagation on fp16 g: h = nd9[v]*sum(g[src]) + a0[v] ------------
// lane split: sub = lane>>3 picks one of 8 edges, (lane&7)*8 picks 8 fp16
// classes (16B). One dwordx4 gathers 8 rows x 16B = 1KB per wave instr.
template<bool LAST>
__global__ __launch_bounds__(256) void k_prop(const _Float16* __restrict__ g,
                                              const float* __restrict__ a0,
                                              const int* __restrict__ esrc,
                                              const int* __restrict__ offs,
                                              const float* __restrict__ nd9,
                                              const float* __restrict__ ns,
                                              void* __restrict__ out, int N) {
    const int lane = threadIdx.x & 63;
    const int wid  = threadIdx.x >> 6;
    const int v    = blockIdx.x * 4 + wid;
    if (v >= N) return;

    const int sub = lane >> 3;           // edge slot (0..7)
    const int q8  = (lane & 7) << 3;     // fp16 class octet base
    const int start = offs[v];
    const int end   = offs[v + 1];

    float accA[8] = {0.f,0.f,0.f,0.f,0.f,0.f,0.f,0.f};
    float accB[8] = {0.f,0.f,0.f,0.f,0.f,0.f,0.f,0.f};

    int i = start;
    for (; i + 16 <= end; i += 16) {
        const int s0 = esrc[i + sub];
        const int s1 = esrc[i + 8 + sub];
        const f16x8 r0 = *(const f16x8*)&g[(size_t)s0 * CLS + q8];
        const f16x8 r1 = *(const f16x8*)&g[(size_t)s1 * CLS + q8];
        #pragma unroll
        for (int j = 0; j < 8; ++j) { accA[j] += (float)r0[j]; accB[j] += (float)r1[j]; }
    }
    if (i + 8 <= end) {
        const int s0 = esrc[i + sub];
        const f16x8 r0 = *(const f16x8*)&g[(size_t)s0 * CLS + q8];
        #pragma unroll
        for (int j = 0; j < 8; ++j) accA[j] += (float)r0[j];
        i += 8;
    }
    if (i < end && sub < end - i) {
        const int s0 = esrc[i + sub];
        const f16x8 r0 = *(const f16x8*)&g[(size_t)s0 * CLS + q8];
        #pragma unroll
        for (int j = 0; j < 8; ++j) accB[j] += (float)r0[j];
    }

    float r[8];
    #pragma unroll
    for (int j = 0; j < 8; ++j) {
        float x = accA[j] + accB[j];
        x += __shfl_xor(x, 8);
        x += __shfl_xor(x, 16);
        x += __shfl_xor(x, 32);
        r[j] = x;
    }

    if (sub == 0) {
        const size_t idx = (size_t)v * CLS + q8;
        const float c = nd9[v];
        const float4 t0 = *(const float4*)&a0[idx];
        const float4 t1 = *(const float4*)&a0[idx + 4];
        float h0 = fmaf(c, r[0], t0.x);
        float h1 = fmaf(c, r[1], t0.y);
        float h2 = fmaf(c, r[2], t0.z);
        float h3 = fmaf(c, r[3], t0.w);
        float h4 = fmaf(c, r[4], t1.x);
        float h5 = fmaf(c, r[5], t1.y);
        float h6 = fmaf(c, r[6], t1.z);
        float h7 = fmaf(c, r[7], t1.w);
        if (LAST) {
            float* po = (float*)out + idx;
            *(float4*)(po)     = make_float4(h0, h1, h2, h3);
            *(float4*)(po + 4) = make_float4(h4, h5, h6, h7);
        } else {
            const float s = ns[v];
            f16x8 o;
            o[0] = (_Float16)(s * h0); o[1] = (_Float16)(s * h1);
            o[2] = (_Float16)(s * h2); o[3] = (_Float16)(s * h3);
            o[4] = (_Float16)(s * h4); o[5] = (_Float16)(s * h5);
            o[6] = (_Float16)(s * h6); o[7] = (_Float16)(s * h7);
            *(f16x8*)((_Float16*)out + idx) = o;
        }
    }
}

extern "C" void kernel_launch(void* const* d_in, const int* in_sizes, int n_in,
                              void* d_out, int out_size, void* d_ws, size_t ws_size,
                              hipStream_t stream) {
    const ushort_t* feat = (const ushort_t*)d_in[0];
    const int*      eidx = (const int*)d_in[1];
    const void*     W1   = d_in[2];
    const void*     b1   = d_in[3];
    const void*     W2   = d_in[4];
    const void*     b2   = d_in[5];

    const int N = in_sizes[0] / IN_F;
    const int E = in_sizes[1] / 2;

    char* w = (char*)d_ws;
    auto take = [&](size_t bytes) -> char* {
        char* p = w; w += (bytes + 255) & ~(size_t)255; return p;
    };
    int*      flags = (int*)take(256);
    unsigned* oc    = (unsigned*)take((size_t)N * 4);
    unsigned* ic    = (unsigned*)take((size_t)N * 4);
    float*    ns    = (float*)take((size_t)N * 4);
    float*    nd9   = (float*)take((size_t)N * 4);
    int*      offs  = (int*)take((size_t)(N + 1) * 4);
    int*      curs  = (int*)take((size_t)N * 4);
    int*      esrc  = (int*)take((size_t)E * 4);
    ushort_t* W1t   = (ushort_t*)take((size_t)HID * IN_F * 2);
    ushort_t* W2t   = (ushort_t*)take((size_t)CLS * HID * 2);
    float*    bias1 = (float*)take((size_t)HID * 4);
    float*    bias2 = (float*)take((size_t)CLS * 4);
    float*    h0a0  = (float*)take((size_t)N * CLS * 4);          // h0 then a0
    char*     regG  = take((size_t)N * HID * 2);                  // H1 (bf16), then gA|gB (fp16)
    ushort_t* H1 = (ushort_t*)regG;
    _Float16* gA = (_Float16*)regG;
    _Float16* gB = (_Float16*)(regG + (size_t)N * CLS * 2);

    hipMemsetAsync(oc, 0, (size_t)N * 4, stream);
    hipMemsetAsync(ic, 0, (size_t)N * 4, stream);

    k_probe<<<1, 64, 0, stream>>>(feat, eidx, flags);
    k_prepw<<<256, 256, 0, stream>>>(W1, W2, b1, b2, W1t, W2t, bias1, bias2, flags);

    const int gE = (E + 255) / 256;
    k_degree<<<gE, 256, 0, stream>>>(eidx, E, oc, ic, flags);
    k_norm<<<(N + 255) / 256, 256, 0, stream>>>(oc, ic, ns, nd9, N);
    k_scan<<<1, 1024, 0, stream>>>(ic, N, offs, curs);
    k_scatter<<<gE, 256, 0, stream>>>(eidx, E, curs, esrc, flags);

    // GEMM1: X=feat [N][512] * W1[512][256] -> H1 bf16. BM=64,BN=256, 4 waves over n.
    k_gemm_mfma<64, 256, 1, 4, 4, 4, true, true, true>
        <<<(N + 63) / 64, 256, 0, stream>>>(feat, W1t, bias1, (void*)H1, N, IN_F, flags);
    // GEMM2: X=H1 [N][256] * W2[256][64] -> h0 fp32. BM=128,BN=64, 2x2 waves.
    k_gemm_mfma<128, 64, 2, 2, 4, 2, false, false, false>
        <<<(N + 127) / 128, 256, 0, stream>>>(H1, W2t, bias2, (void*)h0a0, N, HID, flags);

    const int total4 = (N * CLS) / 4;
    k_init<<<(total4 + 255) / 256, 256, 0, stream>>>(h0a0, gA, ns, total4);

    const int gp = (N + 3) / 4;
    for (int it = 0; it < KPOW; ++it) {
        const _Float16* gin = (it & 1) ? gB : gA;
        if (it == KPOW - 1) {
            k_prop<true ><<<gp, 256, 0, stream>>>(gin, h0a0, esrc, offs, nd9, ns, d_out, N);
        } else {
            _Float16* gout = (it & 1) ? gA : gB;
            k_prop<false><<<gp, 256, 0, stream>>>(gin, h0a0, esrc, offs, nd9, ns, (void*)gout, N);
        }
    }
}

// Round 4
// 1528.536 us; speedup vs baseline: 1.9635x; 1.0275x over previous
//
#include <hip/hip_runtime.h>
#include <stdint.h>

#define IN_F 512
#define HID  256
#define CLS  64
#define KPOW 10
#define NPASS 8

typedef unsigned short ushort_t;

typedef __attribute__((ext_vector_type(8))) __bf16    bf16x8;
typedef __attribute__((ext_vector_type(4))) float     f32x4;
typedef __attribute__((ext_vector_type(8))) short     s16x8;
typedef __attribute__((ext_vector_type(8))) _Float16  f16x8;
typedef __attribute__((ext_vector_type(4))) _Float16  f16x4;

__device__ __forceinline__ float b2f(ushort_t u) {
    union { unsigned u; float f; } x; x.u = ((unsigned)u) << 16; return x.f;
}
__device__ __forceinline__ ushort_t f2b(float f) {
    union { float f; unsigned u; } x; x.f = f;
    unsigned u = x.u;
    u += 0x7fffu + ((u >> 16) & 1u);   // round-to-nearest-even
    return (ushort_t)(u >> 16);
}

// async global->LDS, 16B per lane; lds dest must be wave-uniform base (+lane*16)
__device__ __forceinline__ void gll16(const void* g, void* l) {
    __builtin_amdgcn_global_load_lds(
        (const __attribute__((address_space(1))) unsigned int*)g,
        (__attribute__((address_space(3))) unsigned int*)l, 16, 0, 0);
}

// ---- dtype probes: flags[0]=float-inputs-are-fp32, flags[1]=edges-are-int64
__global__ void k_probe(const ushort_t* __restrict__ feat,
                        const int* __restrict__ eidx,
                        int* __restrict__ flags) {
    if (threadIdx.x == 0 && blockIdx.x == 0) {
        int sane = 0;
        for (int i = 0; i < 128; ++i) {
            unsigned u = (unsigned)feat[2 * i] & 0x7fffu;
            unsigned e = u >> 7;
            if (u == 0u || (e >= 100u && e <= 140u)) sane++;
        }
        flags[0] = (sane == 128) ? 0 : 1;   // 1 => fp32 inputs
        int nz = 0;
        for (int i = 0; i < 128; ++i) nz |= eidx[2 * i + 1];
        flags[1] = (nz == 0) ? 1 : 0;       // 1 => int64 edges
    }
}

__device__ __forceinline__ int edge_at(const int* __restrict__ e, long long i, int wide) {
    return wide ? (int)(((const long long*)e)[i]) : e[i];
}

// ---- pack edges to int32 + degree histogram (one read of eidx) -------------
__global__ void k_pack(const int* __restrict__ eidx, int E,
                       int* __restrict__ es32, int* __restrict__ ed32,
                       unsigned* __restrict__ oc, unsigned* __restrict__ ic,
                       const int* __restrict__ flags) {
    const int wide = flags[1];
    int e = blockIdx.x * blockDim.x + threadIdx.x;
    if (e < E) {
        const int s = edge_at(eidx, e, wide);
        const int d = edge_at(eidx, (long long)E + e, wide);
        es32[e] = s;
        ed32[e] = d;
        atomicAdd(&oc[s], 1u);
        atomicAdd(&ic[d], 1u);
    }
}

// ---------------- norms ----------------
__global__ void k_norm(const unsigned* __restrict__ oc, const unsigned* __restrict__ ic,
                       float* __restrict__ ns, float* __restrict__ nd9, int N) {
    int i = blockIdx.x * blockDim.x + threadIdx.x;
    if (i < N) {
        ns[i]  = rsqrtf(fmaxf((float)oc[i], 1.0f));
        nd9[i] = 0.9f * rsqrtf(fmaxf((float)ic[i], 1.0f));
    }
}

// ---------------- single-block exclusive scan (wave-shuffle based) ----------
__global__ void k_scan(const unsigned* __restrict__ cnt, int n,
                       int* __restrict__ offs, int* __restrict__ cursor) {
    __shared__ unsigned ws[16];
    __shared__ unsigned tot;
    const int t    = threadIdx.x;        // 0..1023
    const int lane = t & 63;
    const int wid  = t >> 6;
    unsigned carry = 0;
    for (int base = 0; base < n; base += 1024) {
        const int i = base + t;
        const unsigned v = (i < n) ? cnt[i] : 0u;
        unsigned x = v;
        #pragma unroll
        for (int d = 1; d < 64; d <<= 1) {
            unsigned y = __shfl_up(x, d);
            if (lane >= d) x += y;
        }
        if (lane == 63) ws[wid] = x;
        __syncthreads();
        if (wid == 0) {
            const unsigned wv = (lane < 16) ? ws[lane] : 0u;
            unsigned wx = wv;
            #pragma unroll
            for (int d = 1; d < 16; d <<= 1) {
                unsigned y = __shfl_up(wx, d);
                if (lane >= d) wx += y;
            }
            if (lane < 16) ws[lane] = wx - wv;
            if (lane == 15) tot = wx;
        }
        __syncthreads();
        if (i < n) {
            const int o = (int)(carry + ws[wid] + (x - v));
            offs[i]   = o;
            cursor[i] = o;
        }
        carry += tot;
        __syncthreads();
    }
    if (t == 0) offs[n] = (int)carry;
}

// ---- multipass scatter: pass p only commits edges with dst in its range ----
// Writes per pass land in a ~12.8MB/NPASS window => L2-resident, no partial-
// line HBM writebacks. Pass-major block order keeps co-resident blocks on
// (mostly) the same pass.
__global__ __launch_bounds__(256) void k_scatter_mp(const int* __restrict__ es32,
                                                    const int* __restrict__ ed32,
                                                    int E, int* __restrict__ cursor,
                                                    int* __restrict__ esrc,
                                                    int range, int bpp) {
    const int pass = blockIdx.x / bpp;
    const int b    = blockIdx.x % bpp;
    const int lo   = pass * range;
    const int hi   = lo + range;

    const int stride = bpp * 256 * 4;
    for (int e = (b * 256 + threadIdx.x) * 4; e + 3 < E; e += stride) {
        const int4 d = *(const int4*)&ed32[e];
        const int4 s = *(const int4*)&es32[e];
        if (d.x >= lo && d.x < hi) esrc[atomicAdd(&cursor[d.x], 1)] = s.x;
        if (d.y >= lo && d.y < hi) esrc[atomicAdd(&cursor[d.y], 1)] = s.y;
        if (d.z >= lo && d.z < hi) esrc[atomicAdd(&cursor[d.z], 1)] = s.z;
        if (d.w >= lo && d.w < hi) esrc[atomicAdd(&cursor[d.w], 1)] = s.w;
    }
    // remainder edges (E % 4): handled once, unfiltered, by the last block
    if (blockIdx.x == gridDim.x - 1 && threadIdx.x < (E & 3)) {
        const int e = (E & ~3) + threadIdx.x;
        const int d = ed32[e];
        esrc[atomicAdd(&cursor[d], 1)] = es32[e];
    }
}

// ---- pre-transpose weights to bf16 [N][K] and biases to fp32 ---------------
__global__ void k_prepw(const void* __restrict__ W1, const void* __restrict__ W2,
                        const void* __restrict__ b1, const void* __restrict__ b2,
                        ushort_t* __restrict__ W1t, ushort_t* __restrict__ W2t,
                        float* __restrict__ bias1, float* __restrict__ bias2,
                        const int* __restrict__ flags) {
    const int f32 = flags[0];
    const int stride = gridDim.x * blockDim.x;
    int t = blockIdx.x * blockDim.x + threadIdx.x;
    for (int i = t; i < IN_F * HID; i += stride) {
        int k = i / HID, n = i % HID;       // coalesced read over n
        float v = f32 ? ((const float*)W1)[i] : b2f(((const ushort_t*)W1)[i]);
        W1t[(size_t)n * IN_F + k] = f2b(v);
    }
    for (int i = t; i < HID * CLS; i += stride) {
        int k = i / CLS, n = i % CLS;
        float v = f32 ? ((const float*)W2)[i] : b2f(((const ushort_t*)W2)[i]);
        W2t[(size_t)n * HID + k] = f2b(v);
    }
    if (t < HID) bias1[t] = f32 ? ((const float*)b1)[t] : b2f(((const ushort_t*)b1)[t]);
    if (t < CLS) bias2[t] = f32 ? ((const float*)b2)[t] : b2f(((const ushort_t*)b2)[t]);
}

// ---------------- MFMA GEMM: C[M][BN] = act(X[M][K] * W[K][BN] + bias) ------
template<int BM, int BN, int WM, int WN, int MF, int NF, bool RELU, bool OUT_BF16, bool A_DYN>
__global__ __launch_bounds__(256) void k_gemm_mfma(const void* __restrict__ Xv,
                                                   const ushort_t* __restrict__ Wt,
                                                   const float* __restrict__ biasf,
                                                   void* __restrict__ Cv,
                                                   int M, int K,
                                                   const int* __restrict__ flags) {
    __shared__ ushort_t Ws[BN * 64];
    __shared__ ushort_t Xs[BM * 64];

    const bool xF32 = A_DYN ? (flags[0] != 0) : false;
    const int tid  = threadIdx.x;
    const int lane = tid & 63;
    const int wid  = tid >> 6;
    const int wr   = wid / WN;
    const int wc   = wid % WN;
    const int l15  = lane & 15;
    const int lhi  = lane >> 4;
    const int mbase = blockIdx.x * BM;

    f32x4 acc[MF][NF];
    #pragma unroll
    for (int mf = 0; mf < MF; ++mf)
        #pragma unroll
        for (int nf = 0; nf < NF; ++nf)
            acc[mf][nf] = (f32x4){0.f, 0.f, 0.f, 0.f};

    for (int kt = 0; kt < K; kt += 64) {
        constexpr int CW = (BN * 8) / 256;
        #pragma unroll
        for (int i = 0; i < CW; ++i) {
            const int cid = i * 256 + tid;
            const int n   = cid >> 3;
            const int c   = (cid & 7) ^ (n & 7);           // inverse swizzle on src
            const ushort_t* src = Wt + (size_t)n * K + kt + c * 8;
            void* dst = (void*)((char*)Ws + (size_t)(i * 256 + wid * 64) * 16);
            gll16((const void*)src, dst);
        }
        constexpr int CX = (BM * 8) / 256;
        #pragma unroll
        for (int i = 0; i < CX; ++i) {
            const int cid = i * 256 + tid;
            const int m   = cid >> 3;
            const int c0  = cid & 7;
            int gr = mbase + m; if (gr >= M) gr = M - 1;
            s16x8 val;
            if (xF32) {
                const float* xp = (const float*)Xv + (size_t)gr * K + kt + c0 * 8;
                const float4 f0 = *(const float4*)(xp);
                const float4 f1 = *(const float4*)(xp + 4);
                val[0] = (short)f2b(f0.x); val[1] = (short)f2b(f0.y);
                val[2] = (short)f2b(f0.z); val[3] = (short)f2b(f0.w);
                val[4] = (short)f2b(f1.x); val[5] = (short)f2b(f1.y);
                val[6] = (short)f2b(f1.z); val[7] = (short)f2b(f1.w);
            } else {
                val = *(const s16x8*)((const ushort_t*)Xv + (size_t)gr * K + kt + c0 * 8);
            }
            *(s16x8*)&Xs[(size_t)(m * 8 + (c0 ^ (m & 7))) * 8] = val;
        }
        __syncthreads();

        #pragma unroll
        for (int ks = 0; ks < 2; ++ks) {
            const int k4 = ks * 4 + lhi;
            bf16x8 wf[NF];
            bf16x8 xf[MF];
            #pragma unroll
            for (int nf = 0; nf < NF; ++nf) {
                const int n = wc * (NF * 16) + nf * 16 + l15;
                wf[nf] = *(const bf16x8*)&Ws[(size_t)(n * 8 + (k4 ^ (n & 7))) * 8];
            }
            #pragma unroll
            for (int mf = 0; mf < MF; ++mf) {
                const int m = wr * (MF * 16) + mf * 16 + l15;
                xf[mf] = *(const bf16x8*)&Xs[(size_t)(m * 8 + (k4 ^ (m & 7))) * 8];
            }
            #pragma unroll
            for (int mf = 0; mf < MF; ++mf)
                #pragma unroll
                for (int nf = 0; nf < NF; ++nf)
                    acc[mf][nf] = __builtin_amdgcn_mfma_f32_16x16x32_bf16(
                        wf[nf], xf[mf], acc[mf][nf], 0, 0, 0);
        }
        __syncthreads();
    }

    #pragma unroll
    for (int nf = 0; nf < NF; ++nf) {
        const int nb = wc * (NF * 16) + nf * 16 + lhi * 4;
        const float4 bb = *(const float4*)&biasf[nb];
        #pragma unroll
        for (int mf = 0; mf < MF; ++mf) {
            const int row = mbase + wr * (MF * 16) + mf * 16 + l15;
            if (row < M) {
                float v0 = acc[mf][nf][0] + bb.x;
                float v1 = acc[mf][nf][1] + bb.y;
                float v2 = acc[mf][nf][2] + bb.z;
                float v3 = acc[mf][nf][3] + bb.w;
                if (RELU) {
                    v0 = fmaxf(v0, 0.f); v1 = fmaxf(v1, 0.f);
                    v2 = fmaxf(v2, 0.f); v3 = fmaxf(v3, 0.f);
                }
                if (OUT_BF16) {
                    ushort4 o;
                    o.x = f2b(v0); o.y = f2b(v1); o.z = f2b(v2); o.w = f2b(v3);
                    *(ushort4*)((ushort_t*)Cv + (size_t)row * BN + nb) = o;
                } else {
                    *(float4*)((float*)Cv + (size_t)row * BN + nb) = make_float4(v0, v1, v2, v3);
                }
            }
        }
    }
}

// ---- after GEMM2: g0 = fp16(ns*h0) ; a0 = 0.1*h0 (in place) ----------------
__global__ void k_init(float* __restrict__ h0a0, _Float16* __restrict__ g0,
                       const float* __restrict__ ns, int total4) {
    int i = blockIdx.x * blockDim.x + threadIdx.x;
    if (i < total4) {
        const int base = i * 4;
        float4 v = *(const float4*)&h0a0[base];
        const float s = ns[base >> 6];
        f16x4 o;
        o[0] = (_Float16)(s * v.x); o[1] = (_Float16)(s * v.y);
        o[2] = (_Float16)(s * v.z); o[3] = (_Float16)(s * v.w);
        *(f16x4*)&g0[base] = o;
        *(float4*)&h0a0[base] = make_float4(0.1f * v.x, 0.1f * v.y, 0.1f * v.z, 0.1f * v.w);
    }
}

// ---- pull propagation on fp16 g: h = nd9[v]*sum(g[src]) + a0[v] ------------
// sub = lane>>3 picks one of 8 edges, (lane&7)*8 picks 8 fp16 classes (16B).
// 32-edge unroll: 4 independent 1KB gathers in flight per wave.
template<bool LAST>
__global__ __launch_bounds__(256) void k_prop(const _Float16* __restrict__ g,
                                              const float* __restrict__ a0,
                                              const int* __restrict__ esrc,
                                              const int* __restrict__ offs,
                                              const float* __restrict__ nd9,
                                              const float* __restrict__ ns,
                                              void* __restrict__ out, int N) {
    const int lane = threadIdx.x & 63;
    const int wid  = threadIdx.x >> 6;
    const int v    = blockIdx.x * 4 + wid;
    if (v >= N) return;

    const int sub = lane >> 3;           // edge slot (0..7)
    const int q8  = (lane & 7) << 3;     // fp16 class octet base
    const int start = offs[v];
    const int end   = offs[v + 1];

    float aA[8] = {0.f,0.f,0.f,0.f,0.f,0.f,0.f,0.f};
    float aB[8] = {0.f,0.f,0.f,0.f,0.f,0.f,0.f,0.f};
    float aC[8] = {0.f,0.f,0.f,0.f,0.f,0.f,0.f,0.f};
    float aD[8] = {0.f,0.f,0.f,0.f,0.f,0.f,0.f,0.f};

    int i = start;
    for (; i + 32 <= end; i += 32) {
        const int s0 = esrc[i + sub];
        const int s1 = esrc[i + 8  + sub];
        const int s2 = esrc[i + 16 + sub];
        const int s3 = esrc[i + 24 + sub];
        const f16x8 r0 = *(const f16x8*)&g[(size_t)s0 * CLS + q8];
        const f16x8 r1 = *(const f16x8*)&g[(size_t)s1 * CLS + q8];
        const f16x8 r2 = *(const f16x8*)&g[(size_t)s2 * CLS + q8];
        const f16x8 r3 = *(const f16x8*)&g[(size_t)s3 * CLS + q8];
        #pragma unroll
        for (int j = 0; j < 8; ++j) {
            aA[j] += (float)r0[j]; aB[j] += (float)r1[j];
            aC[j] += (float)r2[j]; aD[j] += (float)r3[j];
        }
    }
    if (i + 16 <= end) {
        const int s0 = esrc[i + sub];
        const int s1 = esrc[i + 8 + sub];
        const f16x8 r0 = *(const f16x8*)&g[(size_t)s0 * CLS + q8];
        const f16x8 r1 = *(const f16x8*)&g[(size_t)s1 * CLS + q8];
        #pragma unroll
        for (int j = 0; j < 8; ++j) { aA[j] += (float)r0[j]; aB[j] += (float)r1[j]; }
        i += 16;
    }
    if (i + 8 <= end) {
        const int s0 = esrc[i + sub];
        const f16x8 r0 = *(const f16x8*)&g[(size_t)s0 * CLS + q8];
        #pragma unroll
        for (int j = 0; j < 8; ++j) aC[j] += (float)r0[j];
        i += 8;
    }
    if (i < end && sub < end - i) {
        const int s0 = esrc[i + sub];
        const f16x8 r0 = *(const f16x8*)&g[(size_t)s0 * CLS + q8];
        #pragma unroll
        for (int j = 0; j < 8; ++j) aD[j] += (float)r0[j];
    }

    float r[8];
    #pragma unroll
    for (int j = 0; j < 8; ++j) {
        float x = (aA[j] + aB[j]) + (aC[j] + aD[j]);
        x += __shfl_xor(x, 8);
        x += __shfl_xor(x, 16);
        x += __shfl_xor(x, 32);
        r[j] = x;
    }

    if (sub == 0) {
        const size_t idx = (size_t)v * CLS + q8;
        const float c = nd9[v];
        const float4 t0 = *(const float4*)&a0[idx];
        const float4 t1 = *(const float4*)&a0[idx + 4];
        float h0 = fmaf(c, r[0], t0.x);
        float h1 = fmaf(c, r[1], t0.y);
        float h2 = fmaf(c, r[2], t0.z);
        float h3 = fmaf(c, r[3], t0.w);
        float h4 = fmaf(c, r[4], t1.x);
        float h5 = fmaf(c, r[5], t1.y);
        float h6 = fmaf(c, r[6], t1.z);
        float h7 = fmaf(c, r[7], t1.w);
        if (LAST) {
            float* po = (float*)out + idx;
            *(float4*)(po)     = make_float4(h0, h1, h2, h3);
            *(float4*)(po + 4) = make_float4(h4, h5, h6, h7);
        } else {
            const float s = ns[v];
            f16x8 o;
            o[0] = (_Float16)(s * h0); o[1] = (_Float16)(s * h1);
            o[2] = (_Float16)(s * h2); o[3] = (_Float16)(s * h3);
            o[4] = (_Float16)(s * h4); o[5] = (_Float16)(s * h5);
            o[6] = (_Float16)(s * h6); o[7] = (_Float16)(s * h7);
            *(f16x8*)((_Float16*)out + idx) = o;
        }
    }
}

extern "C" void kernel_launch(void* const* d_in, const int* in_sizes, int n_in,
                              void* d_out, int out_size, void* d_ws, size_t ws_size,
                              hipStream_t stream) {
    const ushort_t* feat = (const ushort_t*)d_in[0];
    const int*      eidx = (const int*)d_in[1];
    const void*     W1   = d_in[2];
    const void*     b1   = d_in[3];
    const void*     W2   = d_in[4];
    const void*     b2   = d_in[5];

    const int N = in_sizes[0] / IN_F;
    const int E = in_sizes[1] / 2;

    char* w = (char*)d_ws;
    auto take = [&](size_t bytes) -> char* {
        char* p = w; w += (bytes + 255) & ~(size_t)255; return p;
    };
    int*      flags = (int*)take(256);
    unsigned* oc    = (unsigned*)take((size_t)N * 4);
    unsigned* ic    = (unsigned*)take((size_t)N * 4);
    float*    ns    = (float*)take((size_t)N * 4);
    float*    nd9   = (float*)take((size_t)N * 4);
    int*      offs  = (int*)take((size_t)(N + 1) * 4);
    int*      curs  = (int*)take((size_t)N * 4);
    int*      esrc  = (int*)take((size_t)E * 4);
    ushort_t* W1t   = (ushort_t*)take((size_t)HID * IN_F * 2);
    ushort_t* W2t   = (ushort_t*)take((size_t)CLS * HID * 2);
    float*    bias1 = (float*)take((size_t)HID * 4);
    float*    bias2 = (float*)take((size_t)CLS * 4);
    float*    h0a0  = (float*)take((size_t)N * CLS * 4);          // h0 then a0
    char*     regG  = take((size_t)N * HID * 2);                  // H1 (bf16), then gA|gB (fp16)
    ushort_t* H1 = (ushort_t*)regG;
    _Float16* gA = (_Float16*)regG;
    _Float16* gB = (_Float16*)(regG + (size_t)N * CLS * 2);

    // es32/ed32 alias h0a0 (dead once scatter completes, before GEMM2 writes h0a0)
    int* es32;
    if ((size_t)E * 8 <= (size_t)N * CLS * 4) es32 = (int*)h0a0;
    else                                      es32 = (int*)take((size_t)E * 8);
    int* ed32 = es32 + E;

    hipMemsetAsync(oc, 0, (size_t)N * 4, stream);
    hipMemsetAsync(ic, 0, (size_t)N * 4, stream);

    k_probe<<<1, 64, 0, stream>>>(feat, eidx, flags);
    k_prepw<<<256, 256, 0, stream>>>(W1, W2, b1, b2, W1t, W2t, bias1, bias2, flags);

    const int gE = (E + 255) / 256;
    k_pack<<<gE, 256, 0, stream>>>(eidx, E, es32, ed32, oc, ic, flags);
    k_norm<<<(N + 255) / 256, 256, 0, stream>>>(oc, ic, ns, nd9, N);
    k_scan<<<1, 1024, 0, stream>>>(ic, N, offs, curs);

    const int range = (N + NPASS - 1) / NPASS;
    const int bpp   = 800;
    k_scatter_mp<<<NPASS * bpp, 256, 0, stream>>>(es32, ed32, E, curs, esrc, range, bpp);

    // GEMM1: X=feat [N][512] * W1[512][256] -> H1 bf16. BM=64,BN=256, 4 waves over n.
    k_gemm_mfma<64, 256, 1, 4, 4, 4, true, true, true>
        <<<(N + 63) / 64, 256, 0, stream>>>(feat, W1t, bias1, (void*)H1, N, IN_F, flags);
    // GEMM2: X=H1 [N][256] * W2[256][64] -> h0 fp32. BM=128,BN=64, 2x2 waves.
    k_gemm_mfma<128, 64, 2, 2, 4, 2, false, false, false>
        <<<(N + 127) / 128, 256, 0, stream>>>(H1, W2t, bias2, (void*)h0a0, N, HID, flags);

    const int total4 = (N * CLS) / 4;
    k_init<<<(total4 + 255) / 256, 256, 0, stream>>>(h0a0, gA, ns, total4);

    const int gp = (N + 3) / 4;
    for (int it = 0; it < KPOW; ++it) {
        const _Float16* gin = (it & 1) ? gB : gA;
        if (it == KPOW - 1) {
            k_prop<true ><<<gp, 256, 0, stream>>>(gin, h0a0, esrc, offs, nd9, ns, d_out, N);
        } else {
            _Float16* gout = (it & 1) ? gA : gB;
            k_prop<false><<<gp, 256, 0, stream>>>(gin, h0a0, esrc, offs, nd9, ns, (void*)gout, N);
        }
    }
}

// Round 5
// 1496.044 us; speedup vs baseline: 2.0062x; 1.0217x over previous
//
#include <hip/hip_runtime.h>
#include <stdint.h>

#define IN_F 512
#define HID  256
#define CLS  64
#define KPOW 10
#define NPASS 8
#define BPP   800
#define PBLK  2048

typedef unsigned short ushort_t;

typedef __attribute__((ext_vector_type(8))) __bf16    bf16x8;
typedef __attribute__((ext_vector_type(4))) float     f32x4;
typedef __attribute__((ext_vector_type(8))) short     s16x8;
typedef __attribute__((ext_vector_type(8))) _Float16  f16x8;
typedef __attribute__((ext_vector_type(4))) _Float16  f16x4;

__device__ __forceinline__ float b2f(ushort_t u) {
    union { unsigned u; float f; } x; x.u = ((unsigned)u) << 16; return x.f;
}
__device__ __forceinline__ ushort_t f2b(float f) {
    union { float f; unsigned u; } x; x.f = f;
    unsigned u = x.u;
    u += 0x7fffu + ((u >> 16) & 1u);   // round-to-nearest-even
    return (ushort_t)(u >> 16);
}

// async global->LDS, 16B per lane; lds dest must be wave-uniform base (+lane*16)
__device__ __forceinline__ void gll16(const void* g, void* l) {
    __builtin_amdgcn_global_load_lds(
        (const __attribute__((address_space(1))) unsigned int*)g,
        (__attribute__((address_space(3))) unsigned int*)l, 16, 0, 0);
}

// ---- dtype probes: flags[0]=float-inputs-are-fp32, flags[1]=edges-are-int64
__global__ void k_probe(const ushort_t* __restrict__ feat,
                        const int* __restrict__ eidx,
                        int* __restrict__ flags) {
    if (threadIdx.x == 0 && blockIdx.x == 0) {
        int sane = 0;
        for (int i = 0; i < 128; ++i) {
            unsigned u = (unsigned)feat[2 * i] & 0x7fffu;
            unsigned e = u >> 7;
            if (u == 0u || (e >= 100u && e <= 140u)) sane++;
        }
        flags[0] = (sane == 128) ? 0 : 1;   // 1 => fp32 inputs
        int nz = 0;
        for (int i = 0; i < 128; ++i) nz |= eidx[2 * i + 1];
        flags[1] = (nz == 0) ? 1 : 0;       // 1 => int64 edges
    }
}

__device__ __forceinline__ int edge_at(const int* __restrict__ e, long long i, int wide) {
    return wide ? (int)(((const long long*)e)[i]) : e[i];
}

// ---- pre-transpose weights to bf16 [N][K] and biases to fp32 ---------------
__global__ void k_prepw(const void* __restrict__ W1, const void* __restrict__ W2,
                        const void* __restrict__ b1, const void* __restrict__ b2,
                        ushort_t* __restrict__ W1t, ushort_t* __restrict__ W2t,
                        float* __restrict__ bias1, float* __restrict__ bias2,
                        const int* __restrict__ flags) {
    const int f32 = flags[0];
    const int stride = gridDim.x * blockDim.x;
    int t = blockIdx.x * blockDim.x + threadIdx.x;
    for (int i = t; i < IN_F * HID; i += stride) {
        int k = i / HID, n = i % HID;
        float v = f32 ? ((const float*)W1)[i] : b2f(((const ushort_t*)W1)[i]);
        W1t[(size_t)n * IN_F + k] = f2b(v);
    }
    for (int i = t; i < HID * CLS; i += stride) {
        int k = i / CLS, n = i % CLS;
        float v = f32 ? ((const float*)W2)[i] : b2f(((const ushort_t*)W2)[i]);
        W2t[(size_t)n * HID + k] = f2b(v);
    }
    if (t < HID) bias1[t] = f32 ? ((const float*)b1)[t] : b2f(((const ushort_t*)b1)[t]);
    if (t < CLS) bias2[t] = f32 ? ((const float*)b2)[t] : b2f(((const ushort_t*)b2)[t]);
}

// ---------------- norms ----------------
__global__ void k_norm(const unsigned* __restrict__ oc, const unsigned* __restrict__ ic,
                       float* __restrict__ ns, float* __restrict__ nd9, int N) {
    int i = blockIdx.x * blockDim.x + threadIdx.x;
    if (i < N) {
        ns[i]  = rsqrtf(fmaxf((float)oc[i], 1.0f));
        nd9[i] = 0.9f * rsqrtf(fmaxf((float)ic[i], 1.0f));
    }
}

// ---------------- single-block exclusive scan (wave-shuffle based) ----------
__global__ void k_scan(const unsigned* __restrict__ cnt, int n,
                       int* __restrict__ offs, int* __restrict__ cursor) {
    __shared__ unsigned ws[16];
    __shared__ unsigned tot;
    const int t    = threadIdx.x;
    const int lane = t & 63;
    const int wid  = t >> 6;
    unsigned carry = 0;
    for (int base = 0; base < n; base += 1024) {
        const int i = base + t;
        const unsigned v = (i < n) ? cnt[i] : 0u;
        unsigned x = v;
        #pragma unroll
        for (int d = 1; d < 64; d <<= 1) {
            unsigned y = __shfl_up(x, d);
            if (lane >= d) x += y;
        }
        if (lane == 63) ws[wid] = x;
        __syncthreads();
        if (wid == 0) {
            const unsigned wv = (lane < 16) ? ws[lane] : 0u;
            unsigned wx = wv;
            #pragma unroll
            for (int d = 1; d < 16; d <<= 1) {
                unsigned y = __shfl_up(wx, d);
                if (lane >= d) wx += y;
            }
            if (lane < 16) ws[lane] = wx - wv;
            if (lane == 15) tot = wx;
        }
        __syncthreads();
        if (i < n) {
            const int o = (int)(carry + ws[wid] + (x - v));
            offs[i]   = o;
            cursor[i] = o;
        }
        carry += tot;
        __syncthreads();
    }
    if (t == 0) offs[n] = (int)carry;
}

// ============ fused A: full MLP (GEMM1 -> LDS -> GEMM2) + edge pack =========
// MLP blocks (bid < nmlp): compute h0[64 rows] = relu(X W1 + b1) W2 + b2 into
// h0 (= d_out, dead until final prop write). Pack blocks: int32 edge copy +
// degree histograms (memory-side atomics; MLP hides under their latency).
__global__ __launch_bounds__(256) void k_fusedA(const void* __restrict__ Xv,
                                                const ushort_t* __restrict__ W1t,
                                                const float* __restrict__ bias1,
                                                const ushort_t* __restrict__ W2t,
                                                const float* __restrict__ bias2,
                                                float* __restrict__ h0,
                                                int M,
                                                const int* __restrict__ eidx, int E,
                                                int* __restrict__ es32,
                                                int* __restrict__ ed32,
                                                unsigned* __restrict__ oc,
                                                unsigned* __restrict__ ic,
                                                const int* __restrict__ flags,
                                                int nmlp) {
    __shared__ ushort_t smem[32768];   // 64 KB: Ws[16384]|Xs[4096] -> H1s[16384]|W2s[16384]
    const int bid = blockIdx.x;
    const int tid = threadIdx.x;

    if (bid >= nmlp) {
        // ---------------- pack branch ----------------
        const int wide = flags[1];
        const int b = bid - nmlp;
        for (int e = b * 256 + tid; e < E; e += PBLK * 256) {
            const int s = edge_at(eidx, e, wide);
            const int d = edge_at(eidx, (long long)E + e, wide);
            es32[e] = s;
            ed32[e] = d;
            atomicAdd(&oc[s], 1u);
            atomicAdd(&ic[d], 1u);
        }
        return;
    }

    // ---------------- MLP branch ----------------
    ushort_t* Ws  = smem;            // stage1: [256 n][8 chunk][8 bf16]
    ushort_t* Xs  = smem + 16384;    // stage1: [64 m][8 chunk][8 bf16]
    ushort_t* H1s = smem;            // stage2: [64 m][32 chunk][8 bf16]
    ushort_t* W2s = smem + 16384;    // stage2: [64 n2][32 chunk][8 bf16]

    const bool xF32 = flags[0] != 0;
    const int lane = tid & 63;
    const int wid  = tid >> 6;       // 4 waves
    const int wc   = wid;            // stage1: wave = n-slice of 64
    const int l15  = lane & 15;
    const int lhi  = lane >> 4;
    const int mbase = bid * 64;

    f32x4 acc1[4][4];
    #pragma unroll
    for (int mf = 0; mf < 4; ++mf)
        #pragma unroll
        for (int nf = 0; nf < 4; ++nf)
            acc1[mf][nf] = (f32x4){0.f, 0.f, 0.f, 0.f};

    for (int kt = 0; kt < IN_F; kt += 64) {
        #pragma unroll
        for (int i = 0; i < 8; ++i) {            // Ws: 256 rows x 8 chunks
            const int cid = i * 256 + tid;
            const int n   = cid >> 3;
            const int c   = (cid & 7) ^ (n & 7); // inverse swizzle on src
            gll16(W1t + (size_t)n * IN_F + kt + c * 8,
                  (char*)Ws + (size_t)(i * 256 + wid * 64) * 16);
        }
        #pragma unroll
        for (int i = 0; i < 2; ++i) {            // Xs: 64 rows x 8 chunks
            const int cid = i * 256 + tid;
            const int m   = cid >> 3;
            const int c0  = cid & 7;
            int gr = mbase + m; if (gr >= M) gr = M - 1;
            s16x8 val;
            if (xF32) {
                const float* xp = (const float*)Xv + (size_t)gr * IN_F + kt + c0 * 8;
                const float4 f0 = *(const float4*)(xp);
                const float4 f1 = *(const float4*)(xp + 4);
                val[0] = (short)f2b(f0.x); val[1] = (short)f2b(f0.y);
                val[2] = (short)f2b(f0.z); val[3] = (short)f2b(f0.w);
                val[4] = (short)f2b(f1.x); val[5] = (short)f2b(f1.y);
                val[6] = (short)f2b(f1.z); val[7] = (short)f2b(f1.w);
            } else {
                val = *(const s16x8*)((const ushort_t*)Xv + (size_t)gr * IN_F + kt + c0 * 8);
            }
            *(s16x8*)&Xs[(size_t)(m * 8 + (c0 ^ (m & 7))) * 8] = val;
        }
        __syncthreads();

        #pragma unroll
        for (int ks = 0; ks < 2; ++ks) {
            const int k4 = ks * 4 + lhi;
            bf16x8 wf[4], xf[4];
            #pragma unroll
            for (int nf = 0; nf < 4; ++nf) {
                const int n = wc * 64 + nf * 16 + l15;
                wf[nf] = *(const bf16x8*)&Ws[(size_t)(n * 8 + (k4 ^ (n & 7))) * 8];
            }
            #pragma unroll
            for (int mf = 0; mf < 4; ++mf) {
                const int m = mf * 16 + l15;
                xf[mf] = *(const bf16x8*)&Xs[(size_t)(m * 8 + (k4 ^ (m & 7))) * 8];
            }
            #pragma unroll
            for (int mf = 0; mf < 4; ++mf)
                #pragma unroll
                for (int nf = 0; nf < 4; ++nf)
                    acc1[mf][nf] = __builtin_amdgcn_mfma_f32_16x16x32_bf16(
                        wf[nf], xf[mf], acc1[mf][nf], 0, 0, 0);
        }
        __syncthreads();
    }

    // ---- bias1 + relu -> H1s (bf16, swizzled [m][chunk^ (m&7)])
    #pragma unroll
    for (int nf = 0; nf < 4; ++nf) {
        const int n0 = wc * 64 + nf * 16 + lhi * 4;
        const float4 bb = *(const float4*)&bias1[n0];
        #pragma unroll
        for (int mf = 0; mf < 4; ++mf) {
            const int m = mf * 16 + l15;
            float v0 = fmaxf(acc1[mf][nf][0] + bb.x, 0.f);
            float v1 = fmaxf(acc1[mf][nf][1] + bb.y, 0.f);
            float v2 = fmaxf(acc1[mf][nf][2] + bb.z, 0.f);
            float v3 = fmaxf(acc1[mf][nf][3] + bb.w, 0.f);
            ushort4 o;
            o.x = f2b(v0); o.y = f2b(v1); o.z = f2b(v2); o.w = f2b(v3);
            *(ushort4*)&H1s[(size_t)m * 256 + (size_t)(((n0 >> 3) ^ (m & 7)) * 8) + (n0 & 7)] = o;
        }
    }
    // ---- stage W2 tile: 64 rows x 32 chunks
    #pragma unroll
    for (int i = 0; i < 8; ++i) {
        const int cid = i * 256 + tid;
        const int n2  = cid >> 5;
        const int c   = cid & 31;
        const int csrc = (c & 24) | ((c & 7) ^ (n2 & 7));
        gll16(W2t + (size_t)n2 * HID + csrc * 8,
              (char*)W2s + (size_t)(i * 256 + wid * 64) * 16);
    }
    __syncthreads();

    // ---- stage 2: h0[64 x 64] = H1s @ W2 + b2 (wave = m-slice of 16)
    f32x4 acc2[4];
    #pragma unroll
    for (int nf = 0; nf < 4; ++nf) acc2[nf] = (f32x4){0.f, 0.f, 0.f, 0.f};
    #pragma unroll
    for (int ks = 0; ks < 8; ++ks) {
        const int c = ks * 4 + lhi;
        const int m = wid * 16 + l15;
        const bf16x8 xf = *(const bf16x8*)&H1s[(size_t)m * 256 + (size_t)((c ^ (m & 7)) * 8)];
        #pragma unroll
        for (int nf = 0; nf < 4; ++nf) {
            const int n2 = nf * 16 + l15;
            const bf16x8 wf = *(const bf16x8*)&W2s[(size_t)n2 * 256 + (size_t)((c ^ (n2 & 7)) * 8)];
            acc2[nf] = __builtin_amdgcn_mfma_f32_16x16x32_bf16(wf, xf, acc2[nf], 0, 0, 0);
        }
    }
    const int row = mbase + wid * 16 + l15;
    if (row < M) {
        #pragma unroll
        for (int nf = 0; nf < 4; ++nf) {
            const int n2b = nf * 16 + lhi * 4;
            const float4 bb = *(const float4*)&bias2[n2b];
            float4 o = make_float4(acc2[nf][0] + bb.x, acc2[nf][1] + bb.y,
                                   acc2[nf][2] + bb.z, acc2[nf][3] + bb.w);
            *(float4*)&h0[(size_t)row * CLS + n2b] = o;
        }
    }
}

// ============ fused B: multipass scatter + init (g0/a0 from h0) =============
__global__ __launch_bounds__(256) void k_fusedB(const int* __restrict__ es32,
                                                const int* __restrict__ ed32,
                                                int E, int* __restrict__ cursor,
                                                int* __restrict__ esrc, int range,
                                                const float* __restrict__ h0,
                                                _Float16* __restrict__ g0,
                                                _Float16* __restrict__ a0h,
                                                const float* __restrict__ ns,
                                                int total4, int gsc) {
    const int bid = blockIdx.x;
    if (bid < gsc) {
        const int pass = bid / BPP;
        const int b    = bid % BPP;
        const int lo   = pass * range;
        const int hi   = lo + range;
        const int stride = BPP * 256 * 4;
        for (int e = (b * 256 + threadIdx.x) * 4; e + 3 < E; e += stride) {
            const int4 d = *(const int4*)&ed32[e];
            const int4 s = *(const int4*)&es32[e];
            if (d.x >= lo && d.x < hi) esrc[atomicAdd(&cursor[d.x], 1)] = s.x;
            if (d.y >= lo && d.y < hi) esrc[atomicAdd(&cursor[d.y], 1)] = s.y;
            if (d.z >= lo && d.z < hi) esrc[atomicAdd(&cursor[d.z], 1)] = s.z;
            if (d.w >= lo && d.w < hi) esrc[atomicAdd(&cursor[d.w], 1)] = s.w;
        }
        if (bid == gsc - 1 && threadIdx.x < (E & 3)) {
            const int e = (E & ~3) + threadIdx.x;
            const int d = ed32[e];
            esrc[atomicAdd(&cursor[d], 1)] = es32[e];
        }
    } else {
        const int i = (bid - gsc) * 256 + threadIdx.x;
        if (i < total4) {
            const int base = i * 4;
            const float4 v = *(const float4*)&h0[base];
            const float s = ns[base >> 6];
            f16x4 g;
            g[0] = (_Float16)(s * v.x); g[1] = (_Float16)(s * v.y);
            g[2] = (_Float16)(s * v.z); g[3] = (_Float16)(s * v.w);
            *(f16x4*)&g0[base] = g;
            f16x4 a;
            a[0] = (_Float16)(0.1f * v.x); a[1] = (_Float16)(0.1f * v.y);
            a[2] = (_Float16)(0.1f * v.z); a[3] = (_Float16)(0.1f * v.w);
            *(f16x4*)&a0h[base] = a;
        }
    }
}

// ---- sort each dst's src-list ascending (wave-64 bitonic; skip n>64) -------
// Pure permutation of each CSR segment => numerically exact. Gives co-resident
// prop blocks a lockstep 0->N src sweep (L2-windowed gathers).
__global__ __launch_bounds__(256) void k_sortlist(int* __restrict__ esrc,
                                                  const int* __restrict__ offs, int N) {
    const int lane = threadIdx.x & 63;
    const int wid  = threadIdx.x >> 6;
    const int v    = blockIdx.x * 4 + wid;
    if (v >= N) return;
    const int start = offs[v];
    const int n     = offs[v + 1] - start;
    if (n <= 1 || n > 64) return;
    int x = (lane < n) ? esrc[start + lane] : 0x7fffffff;
    for (int k = 2; k <= 64; k <<= 1) {
        for (int j = k >> 1; j >= 1; j >>= 1) {
            const int y = __shfl_xor(x, j);
            const bool dir   = (lane & k) == 0;
            const bool lower = (lane & j) == 0;
            x = (lower == dir) ? min(x, y) : max(x, y);
        }
    }
    if (lane < n) esrc[start + lane] = x;
}

// ---- pull propagation on fp16 g: h = nd9[v]*sum(g[src]) + a0[v] ------------
// sub = lane>>3 picks one of 8 edges, (lane&7)*8 picks 8 fp16 classes (16B).
// 32-edge unroll: 4 independent 1KB gathers in flight per wave.
template<bool LAST>
__global__ __launch_bounds__(256) void k_prop(const _Float16* __restrict__ g,
                                              const _Float16* __restrict__ a0h,
                                              const int* __restrict__ esrc,
                                              const int* __restrict__ offs,
                                              const float* __restrict__ nd9,
                                              const float* __restrict__ ns,
                                              void* __restrict__ out, int N) {
    const int lane = threadIdx.x & 63;
    const int wid  = threadIdx.x >> 6;
    const int v    = blockIdx.x * 4 + wid;
    if (v >= N) return;

    const int sub = lane >> 3;
    const int q8  = (lane & 7) << 3;
    const int start = offs[v];
    const int end   = offs[v + 1];

    float aA[8] = {0.f,0.f,0.f,0.f,0.f,0.f,0.f,0.f};
    float aB[8] = {0.f,0.f,0.f,0.f,0.f,0.f,0.f,0.f};
    float aC[8] = {0.f,0.f,0.f,0.f,0.f,0.f,0.f,0.f};
    float aD[8] = {0.f,0.f,0.f,0.f,0.f,0.f,0.f,0.f};

    int i = start;
    for (; i + 32 <= end; i += 32) {
        const int s0 = esrc[i + sub];
        const int s1 = esrc[i + 8  + sub];
        const int s2 = esrc[i + 16 + sub];
        const int s3 = esrc[i + 24 + sub];
        const f16x8 r0 = *(const f16x8*)&g[(size_t)s0 * CLS + q8];
        const f16x8 r1 = *(const f16x8*)&g[(size_t)s1 * CLS + q8];
        const f16x8 r2 = *(const f16x8*)&g[(size_t)s2 * CLS + q8];
        const f16x8 r3 = *(const f16x8*)&g[(size_t)s3 * CLS + q8];
        #pragma unroll
        for (int j = 0; j < 8; ++j) {
            aA[j] += (float)r0[j]; aB[j] += (float)r1[j];
            aC[j] += (float)r2[j]; aD[j] += (float)r3[j];
        }
    }
    if (i + 16 <= end) {
        const int s0 = esrc[i + sub];
        const int s1 = esrc[i + 8 + sub];
        const f16x8 r0 = *(const f16x8*)&g[(size_t)s0 * CLS + q8];
        const f16x8 r1 = *(const f16x8*)&g[(size_t)s1 * CLS + q8];
        #pragma unroll
        for (int j = 0; j < 8; ++j) { aA[j] += (float)r0[j]; aB[j] += (float)r1[j]; }
        i += 16;
    }
    if (i + 8 <= end) {
        const int s0 = esrc[i + sub];
        const f16x8 r0 = *(const f16x8*)&g[(size_t)s0 * CLS + q8];
        #pragma unroll
        for (int j = 0; j < 8; ++j) aC[j] += (float)r0[j];
        i += 8;
    }
    if (i < end && sub < end - i) {
        const int s0 = esrc[i + sub];
        const f16x8 r0 = *(const f16x8*)&g[(size_t)s0 * CLS + q8];
        #pragma unroll
        for (int j = 0; j < 8; ++j) aD[j] += (float)r0[j];
    }

    float r[8];
    #pragma unroll
    for (int j = 0; j < 8; ++j) {
        float x = (aA[j] + aB[j]) + (aC[j] + aD[j]);
        x += __shfl_xor(x, 8);
        x += __shfl_xor(x, 16);
        x += __shfl_xor(x, 32);
        r[j] = x;
    }

    if (sub == 0) {
        const size_t idx = (size_t)v * CLS + q8;
        const float c = nd9[v];
        const f16x8 t = *(const f16x8*)&a0h[idx];
        float h[8];
        #pragma unroll
        for (int j = 0; j < 8; ++j) h[j] = fmaf(c, r[j], (float)t[j]);
        if (LAST) {
            float* po = (float*)out + idx;
            *(float4*)(po)     = make_float4(h[0], h[1], h[2], h[3]);
            *(float4*)(po + 4) = make_float4(h[4], h[5], h[6], h[7]);
        } else {
            const float s = ns[v];
            f16x8 o;
            #pragma unroll
            for (int j = 0; j < 8; ++j) o[j] = (_Float16)(s * h[j]);
            *(f16x8*)((_Float16*)out + idx) = o;
        }
    }
}

extern "C" void kernel_launch(void* const* d_in, const int* in_sizes, int n_in,
                              void* d_out, int out_size, void* d_ws, size_t ws_size,
                              hipStream_t stream) {
    const ushort_t* feat = (const ushort_t*)d_in[0];
    const int*      eidx = (const int*)d_in[1];
    const void*     W1   = d_in[2];
    const void*     b1   = d_in[3];
    const void*     W2   = d_in[4];
    const void*     b2   = d_in[5];

    const int N = in_sizes[0] / IN_F;
    const int E = in_sizes[1] / 2;

    char* w = (char*)d_ws;
    auto take = [&](size_t bytes) -> char* {
        char* p = w; w += (bytes + 255) & ~(size_t)255; return p;
    };
    int*      flags = (int*)take(256);
    unsigned* oc    = (unsigned*)take((size_t)N * 4);
    unsigned* ic    = (unsigned*)take((size_t)N * 4);
    float*    ns    = (float*)take((size_t)N * 4);
    float*    nd9   = (float*)take((size_t)N * 4);
    int*      offs  = (int*)take((size_t)(N + 1) * 4);
    int*      curs  = (int*)take((size_t)N * 4);
    int*      esrc  = (int*)take((size_t)E * 4);
    ushort_t* W1t   = (ushort_t*)take((size_t)HID * IN_F * 2);
    ushort_t* W2t   = (ushort_t*)take((size_t)CLS * HID * 2);
    float*    bias1 = (float*)take((size_t)HID * 4);
    float*    bias2 = (float*)take((size_t)CLS * 4);
    int*      es32  = (int*)take((size_t)E * 8);               // es | ed
    int*      ed32  = es32 + E;
    _Float16* gA    = (_Float16*)take((size_t)N * CLS * 2);
    _Float16* gB    = (_Float16*)take((size_t)N * CLS * 2);
    _Float16* a0h   = (_Float16*)take((size_t)N * CLS * 2);

    float* h0 = (float*)d_out;   // h0 lives in d_out until init consumes it

    hipMemsetAsync(oc, 0, (size_t)N * 4, stream);
    hipMemsetAsync(ic, 0, (size_t)N * 4, stream);

    k_probe<<<1, 64, 0, stream>>>(feat, eidx, flags);
    k_prepw<<<256, 256, 0, stream>>>(W1, W2, b1, b2, W1t, W2t, bias1, bias2, flags);

    // fused A: MLP blocks first, then pack blocks
    const int nmlp = (N + 63) / 64;
    k_fusedA<<<nmlp + PBLK, 256, 0, stream>>>(feat, W1t, bias1, W2t, bias2, h0,
                                              N, eidx, E, es32, ed32, oc, ic,
                                              flags, nmlp);

    k_norm<<<(N + 255) / 256, 256, 0, stream>>>(oc, ic, ns, nd9, N);
    k_scan<<<1, 1024, 0, stream>>>(ic, N, offs, curs);

    // fused B: scatter blocks first, then init blocks
    const int range  = (N + NPASS - 1) / NPASS;
    const int gsc    = NPASS * BPP;
    const int total4 = (N * CLS) / 4;
    const int ginit  = (total4 + 255) / 256;
    k_fusedB<<<gsc + ginit, 256, 0, stream>>>(es32, ed32, E, curs, esrc, range,
                                              h0, gA, a0h, ns, total4, gsc);

    k_sortlist<<<(N + 3) / 4, 256, 0, stream>>>(esrc, offs, N);

    const int gp = (N + 3) / 4;
    for (int it = 0; it < KPOW; ++it) {
        const _Float16* gin = (it & 1) ? gB : gA;
        if (it == KPOW - 1) {
            k_prop<true ><<<gp, 256, 0, stream>>>(gin, a0h, esrc, offs, nd9, ns, d_out, N);
        } else {
            _Float16* gout = (it & 1) ? gA : gB;
            k_prop<false><<<gp, 256, 0, stream>>>(gin, a0h, esrc, offs, nd9, ns, (void*)gout, N);
        }
    }
}